// Round 1
// baseline (9.413 us; speedup 1.0000x reference)
//
#include <hip/hip_runtime.h>
#include <math.h>

// Reference collapses analytically:
//   - Initial |0...0> + per-wire single-qubit gates => product state.
//   - CNOT(0,1) commutes with Z_0; CNOT(i,i+1) for i>=1 don't touch qubit 0
//     => <Z_0> unchanged by the entangling layer.
//   - <Z> of RY(b)RX(a)|0> = cos(a)*cos(b).
// => out[b] = sigmoid( cos(params[0]) * cos( dot(x[b,:], W[0,:]) ) )

#define BATCH 4096
#define FEAT  256

__global__ __launch_bounds__(256) void gate_circuit_collapsed(
    const float* __restrict__ x,      // [BATCH, FEAT]
    const float* __restrict__ W,      // [14, FEAT] (only row 0 used)
    const float* __restrict__ params, // [14] (only params[0] used)
    float* __restrict__ out)          // [BATCH]
{
    const int wave = threadIdx.x >> 6;      // 4 waves per block
    const int lane = threadIdx.x & 63;      // wavefront = 64 on CDNA
    const int row  = blockIdx.x * 4 + wave; // one batch row per wave

    // 64 lanes x float4 = 256 floats: exactly one row / one W-row.
    const float4 w4 = reinterpret_cast<const float4*>(W)[lane];
    const float4 x4 = reinterpret_cast<const float4*>(x + (size_t)row * FEAT)[lane];

    float dot = x4.x * w4.x + x4.y * w4.y + x4.z * w4.z + x4.w * w4.w;

    // 64-lane butterfly reduction
    #pragma unroll
    for (int off = 32; off >= 1; off >>= 1)
        dot += __shfl_xor(dot, off, 64);

    if (lane == 0) {
        const float z = cosf(params[0]) * cosf(dot);
        out[row] = 1.0f / (1.0f + expf(-z)); // sigmoid
    }
}

extern "C" void kernel_launch(void* const* d_in, const int* in_sizes, int n_in,
                              void* d_out, int out_size, void* d_ws, size_t ws_size,
                              hipStream_t stream) {
    const float* x = (const float*)d_in[0];
    const float* W = (const float*)d_in[1];
    const float* p = (const float*)d_in[2];
    float* out     = (float*)d_out;

    gate_circuit_collapsed<<<dim3(BATCH / 4), dim3(256), 0, stream>>>(x, W, p, out);
}